// Round 13
// baseline (291.640 us; speedup 1.0000x reference)
//
#include <hip/hip_runtime.h>
#include <stdint.h>

#define N_NODES 50000
#define N_EDGES 600000
#define NCLS    47
#define SCAN_TPB 512
#define SCAN_BLOCKS ((N_NODES + SCAN_TPB - 1) / SCAN_TPB)   // 98

typedef __attribute__((ext_vector_type(8))) short short8;
typedef __attribute__((ext_vector_type(4))) float f32x4;

static __device__ __forceinline__ float bf2f(uint16_t h) {
    union { uint32_t u; float f; } c; c.u = ((uint32_t)h) << 16; return c.f;
}
static __device__ __forceinline__ float bf2fs(short h) { return bf2f((uint16_t)h); }
static __device__ __forceinline__ uint16_t f2bf(float f) {
    union { float f; uint32_t u; } c; c.f = f;
    uint32_t u = c.u;
    return (uint16_t)((u + 0x7fffu + ((u >> 16) & 1u)) >> 16); // RNE
}

// ---------------- f32 matrix -> bf16 (hi only)
__global__ __launch_bounds__(256) void k_split(const float4* __restrict__ x,
                                               ushort4* __restrict__ xh) {
    int i = blockIdx.x * 256 + threadIdx.x;   // 1.6M float4s
    float4 v = x[i];
    ushort4 h;
    h.x = f2bf(v.x);
    h.y = f2bf(v.y);
    h.z = f2bf(v.z);
    h.w = f2bf(v.w);
    xh[i] = h;
}

// ---------- degree count straight from edge_index (int64-or-int32)
__global__ __launch_bounds__(256) void k_deg(const int* __restrict__ ei,
                                             int* __restrict__ deg) {
    __shared__ int is64;
    {
        int lane = threadIdx.x;
        if (lane < 64) {
            int f = ei[2 * lane + 1] | ei[2 * lane + 129]; // 128 hi-words if int64
            unsigned long long m = __ballot(f != 0);
            if (lane == 0) is64 = (m == 0ULL) ? 1 : 0;
        }
        __syncthreads();
    }
    int e = blockIdx.x * 256 + threadIdx.x;
    if (e < N_EDGES) {
        int d = is64 ? ei[2 * (N_EDGES + e)] : ei[N_EDGES + e];
        d = min(max(d, 0), N_NODES - 1);
        atomicAdd(&deg[d], 1);
    }
}

// ------------------------------------------- scan stage 1: per-block partials
__global__ __launch_bounds__(SCAN_TPB) void k_scan1(const int* __restrict__ deg,
                                                    int* __restrict__ partial) {
    int t = blockIdx.x * SCAN_TPB + threadIdx.x;
    int v = (t < N_NODES) ? deg[t] : 0;
#pragma unroll
    for (int o = 1; o < 64; o <<= 1) v += __shfl_xor(v, o);
    __shared__ int ws[SCAN_TPB / 64];
    int lane = threadIdx.x & 63, w = threadIdx.x >> 6;
    if (lane == 0) ws[w] = v;
    __syncthreads();
    if (threadIdx.x == 0) {
        int s = 0;
#pragma unroll
        for (int i = 0; i < SCAN_TPB / 64; ++i) s += ws[i];
        partial[blockIdx.x] = s;
    }
}

// ---------------------------- scan stage 2: exclusive scan of 98 partials
__global__ __launch_bounds__(128) void k_scan2(int* __restrict__ partial) {
    __shared__ int sh[128];
    int t = threadIdx.x;
    int v = (t < SCAN_BLOCKS) ? partial[t] : 0;
    sh[t] = v;
    __syncthreads();
    for (int o = 1; o < 128; o <<= 1) {
        int u = (t >= o) ? sh[t - o] : 0;
        __syncthreads();
        sh[t] += u;
        __syncthreads();
    }
    if (t < SCAN_BLOCKS) partial[t] = sh[t] - v; // exclusive
}

// --------------- scan stage 3: block-local exclusive scan + offset, emit CSR
__global__ __launch_bounds__(SCAN_TPB) void k_scan3(const int* __restrict__ deg,
                                                    const int* __restrict__ partial,
                                                    int* __restrict__ row_start,
                                                    int* __restrict__ fill,
                                                    float* __restrict__ inv_deg) {
    int tb = threadIdx.x;
    int t = blockIdx.x * SCAN_TPB + tb;
    int v = (t < N_NODES) ? deg[t] : 0;
    int lane = tb & 63, w = tb >> 6;
    int inc = v;
#pragma unroll
    for (int o = 1; o < 64; o <<= 1) {
        int u = __shfl_up(inc, o);
        if (lane >= o) inc += u;
    }
    __shared__ int wsum[SCAN_TPB / 64];
    if (lane == 63) wsum[w] = inc;
    __syncthreads();
    int woff = 0;
    for (int i = 0; i < w; ++i) woff += wsum[i];
    int excl = partial[blockIdx.x] + woff + (inc - v);
    if (t < N_NODES) {
        row_start[t] = excl;
        fill[t] = excl;
        inv_deg[t] = 1.0f / (float)(v > 0 ? v : 1);
    }
}

// --------------------------- bucket fill (reads edge_index directly)
__global__ __launch_bounds__(256) void k_fill(const int* __restrict__ ei,
                                              int* __restrict__ fill,
                                              int* __restrict__ elist) {
    __shared__ int is64;
    {
        int lane = threadIdx.x;
        if (lane < 64) {
            int f = ei[2 * lane + 1] | ei[2 * lane + 129];
            unsigned long long m = __ballot(f != 0);
            if (lane == 0) is64 = (m == 0ULL) ? 1 : 0;
        }
        __syncthreads();
    }
    int e = blockIdx.x * 256 + threadIdx.x;
    if (e < N_EDGES) {
        int s, d;
        if (is64) { s = ei[2 * e]; d = ei[2 * (N_EDGES + e)]; }
        else      { s = ei[e];     d = ei[N_EDGES + e]; }
        s = min(max(s, 0), N_NODES - 1);
        d = min(max(d, 0), N_NODES - 1);
        int pos = atomicAdd(&fill[d], 1);
        elist[pos] = s;
    }
}

// -------------- weight prep: transpose W[k][col] -> img[col][k], bf16 hi + lo
// ALL matrices get the bank-conflict swizzle baked in: chunk (k>>3) ^ (col&15).
__global__ __launch_bounds__(256) void k_prepw(const float* Wl0, const float* Wr0,
                                               const float* Wl1, const float* Wr1,
                                               const float* Wl2, const float* Wr2,
                                               uint16_t* __restrict__ img) {
    int b = blockIdx.x >> 6;
    int sub = blockIdx.x & 63;
    const float* W; int ncol, npad; uint16_t* o;
    switch (b) {
        case 0: W = Wl0; ncol = 128; npad = 128; o = img;           break;
        case 1: W = Wr0; ncol = 128; npad = 128; o = img + 32768;   break;
        case 2: W = Wl1; ncol = 128; npad = 128; o = img + 65536;   break;
        case 3: W = Wr1; ncol = 128; npad = 128; o = img + 98304;   break;
        case 4: W = Wl2; ncol = 47;  npad = 48;  o = img + 131072;  break;
        default:W = Wr2; ncol = 47;  npad = 48;  o = img + 143360;  break;
    }
    int elems = npad * 128;
    int i = sub * 256 + threadIdx.x;
    if (i < elems) {
        int col = i % npad, k = i / npad;
        float v = (col < ncol) ? W[k * ncol + col] : 0.f;
        uint16_t h = f2bf(v);
        uint16_t l = f2bf(v - bf2f(h));
        int idx = col * 128 + (((k >> 3) ^ (col & 15)) << 3) + (k & 7);
        o[idx] = h;
        o[idx + elems] = l;
    }
}

// ------- FUSED layers 0/1: out = relu(agg(Ain)@Wl + Ain@Wr + b)
// 512 thr / 8 waves / 16 rows/wave / 128 rows/block (grid 391), LDS-W.
// Phase 1: each lane aggregates ITS OWN MFMA A-fragment elements
// (row = lane&15, elems (lane>>4)*8 + s*32, s=0..3) -> agg lands in registers.
__global__ __launch_bounds__(512, 4) void k_gemm(const uint16_t* __restrict__ Ain,
                                                 const int* __restrict__ row_start,
                                                 const int* __restrict__ degv,
                                                 const float* __restrict__ inv_deg,
                                                 const int* __restrict__ elist,
                                                 const uint16_t* __restrict__ wl,
                                                 const uint16_t* __restrict__ wr,
                                                 const float* __restrict__ bias,
                                                 uint16_t* __restrict__ outh) {
    __shared__ __align__(16) uint16_t ldsW[32768];   // 64 KB: one matrix hi+lo
    int tid = threadIdx.x;
    int lane = tid & 63, wv = tid >> 6;              // 8 waves
    int li = lane & 15, g4 = lane >> 4;
    int mrow = blockIdx.x * 128 + wv * 16 + li;
    int r0 = min(mrow, N_NODES - 1);

    // ---- phase 1: in-register mean aggregation of row r0's fragment elems
    float ag[4][8];
#pragma unroll
    for (int s = 0; s < 4; ++s)
#pragma unroll
        for (int k = 0; k < 8; ++k) ag[s][k] = 0.f;
    {
        int rs = row_start[r0];
        int d = degv[r0];
        int i = 0;
        for (; i + 1 < d; i += 2) {                  // 8 loads in flight
            int n0 = elist[rs + i];
            int n1 = elist[rs + i + 1];
            const uint16_t* p0 = &Ain[(size_t)n0 * 128 + g4 * 8];
            const uint16_t* p1 = &Ain[(size_t)n1 * 128 + g4 * 8];
            short8 u0 = *(const short8*)&p0[0];
            short8 u1 = *(const short8*)&p0[32];
            short8 u2 = *(const short8*)&p0[64];
            short8 u3 = *(const short8*)&p0[96];
            short8 v0 = *(const short8*)&p1[0];
            short8 v1 = *(const short8*)&p1[32];
            short8 v2 = *(const short8*)&p1[64];
            short8 v3 = *(const short8*)&p1[96];
#pragma unroll
            for (int k = 0; k < 8; ++k) {
                ag[0][k] += bf2fs(u0[k]) + bf2fs(v0[k]);
                ag[1][k] += bf2fs(u1[k]) + bf2fs(v1[k]);
                ag[2][k] += bf2fs(u2[k]) + bf2fs(v2[k]);
                ag[3][k] += bf2fs(u3[k]) + bf2fs(v3[k]);
            }
        }
        if (i < d) {
            int n0 = elist[rs + i];
            const uint16_t* p0 = &Ain[(size_t)n0 * 128 + g4 * 8];
            short8 u0 = *(const short8*)&p0[0];
            short8 u1 = *(const short8*)&p0[32];
            short8 u2 = *(const short8*)&p0[64];
            short8 u3 = *(const short8*)&p0[96];
#pragma unroll
            for (int k = 0; k < 8; ++k) {
                ag[0][k] += bf2fs(u0[k]);
                ag[1][k] += bf2fs(u1[k]);
                ag[2][k] += bf2fs(u2[k]);
                ag[3][k] += bf2fs(u3[k]);
            }
        }
    }
    short8 a1[4];
    {
        float sc = inv_deg[r0];
#pragma unroll
        for (int s = 0; s < 4; ++s)
#pragma unroll
            for (int k = 0; k < 8; ++k)
                a1[s][k] = (short)f2bf(ag[s][k] * sc);
    }

    f32x4 acc[8];
#pragma unroll
    for (int t = 0; t < 8; ++t) acc[t] = (f32x4){0.f, 0.f, 0.f, 0.f};

#pragma unroll
    for (int arr = 0; arr < 2; ++arr) {
        {   // stage this arr's weight image (linear copy; swizzle pre-applied)
            const uint4* g = (const uint4*)(arr ? wr : wl);
            uint4* l = (uint4*)ldsW;
#pragma unroll
            for (int j2 = 0; j2 < 8; ++j2)           // 4096 uint4 / 512 thr
                l[j2 * 512 + tid] = g[j2 * 512 + tid];
        }
        __syncthreads();
#pragma unroll
        for (int s = 0; s < 4; ++s) {
            short8 av;
            if (arr == 0) av = a1[s];
            else av = *(const short8*)&Ain[(size_t)r0 * 128 + s * 32 + g4 * 8];
#pragma unroll
            for (int t = 0; t < 8; ++t) {
                int off = (t * 16 + li) * 128 + (((s * 4 + g4) ^ li) << 3);
                short8 bh = *(const short8*)&ldsW[off];
                short8 bl = *(const short8*)&ldsW[off + 16384];
                acc[t] = __builtin_amdgcn_mfma_f32_16x16x32_bf16(av, bh, acc[t], 0, 0, 0);
                acc[t] = __builtin_amdgcn_mfma_f32_16x16x32_bf16(av, bl, acc[t], 0, 0, 0);
            }
        }
        if (arr == 0) __syncthreads();   // drain reads before restaging
    }
    // epilogue: bias + relu, bf16 store.  D layout: col=lane&15, row=(lane>>4)*4+rr
    int rowbase = blockIdx.x * 128 + wv * 16 + g4 * 4;
#pragma unroll
    for (int t = 0; t < 8; ++t) {
        int col = t * 16 + li;
        float bv = bias[col];
#pragma unroll
        for (int rr = 0; rr < 4; ++rr) {
            int row = rowbase + rr;
            if (row < N_NODES)
                outh[(size_t)row * 128 + col] = f2bf(fmaxf(acc[t][rr] + bv, 0.f));
        }
    }
}

// -------- FUSED layer 2: logsoftmax(normalize(agg(Ain)@Wl2 + Ain@Wr2 + b))
__global__ __launch_bounds__(512, 4) void k_gemm2(const uint16_t* __restrict__ Ain,
                                                  const int* __restrict__ row_start,
                                                  const int* __restrict__ degv,
                                                  const float* __restrict__ inv_deg,
                                                  const int* __restrict__ elist,
                                                  const uint16_t* __restrict__ w2,
                                                  const float* __restrict__ bias,
                                                  float* __restrict__ out) {
    __shared__ __align__(16) uint16_t ldsW[24576];   // 48 KB: wl2+wr2, hi+lo
    int tid = threadIdx.x;
    int lane = tid & 63, wv = tid >> 6;
    int li = lane & 15, g4 = lane >> 4;
    int mrow = blockIdx.x * 128 + wv * 16 + li;
    int r = min(mrow, N_NODES - 1);

    {   // stage both layer-2 images (contiguous 24576 u16 = 6144 uint4)
        const uint4* g = (const uint4*)w2;
        uint4* l = (uint4*)ldsW;
#pragma unroll
        for (int j2 = 0; j2 < 12; ++j2)
            l[j2 * 512 + tid] = g[j2 * 512 + tid];
    }

    // ---- phase 1: in-register aggregation (overlaps with staging above)
    float ag[4][8];
#pragma unroll
    for (int s = 0; s < 4; ++s)
#pragma unroll
        for (int k = 0; k < 8; ++k) ag[s][k] = 0.f;
    {
        int rs = row_start[r];
        int d = degv[r];
        int i = 0;
        for (; i + 1 < d; i += 2) {
            int n0 = elist[rs + i];
            int n1 = elist[rs + i + 1];
            const uint16_t* p0 = &Ain[(size_t)n0 * 128 + g4 * 8];
            const uint16_t* p1 = &Ain[(size_t)n1 * 128 + g4 * 8];
            short8 u0 = *(const short8*)&p0[0];
            short8 u1 = *(const short8*)&p0[32];
            short8 u2 = *(const short8*)&p0[64];
            short8 u3 = *(const short8*)&p0[96];
            short8 v0 = *(const short8*)&p1[0];
            short8 v1 = *(const short8*)&p1[32];
            short8 v2 = *(const short8*)&p1[64];
            short8 v3 = *(const short8*)&p1[96];
#pragma unroll
            for (int k = 0; k < 8; ++k) {
                ag[0][k] += bf2fs(u0[k]) + bf2fs(v0[k]);
                ag[1][k] += bf2fs(u1[k]) + bf2fs(v1[k]);
                ag[2][k] += bf2fs(u2[k]) + bf2fs(v2[k]);
                ag[3][k] += bf2fs(u3[k]) + bf2fs(v3[k]);
            }
        }
        if (i < d) {
            int n0 = elist[rs + i];
            const uint16_t* p0 = &Ain[(size_t)n0 * 128 + g4 * 8];
            short8 u0 = *(const short8*)&p0[0];
            short8 u1 = *(const short8*)&p0[32];
            short8 u2 = *(const short8*)&p0[64];
            short8 u3 = *(const short8*)&p0[96];
#pragma unroll
            for (int k = 0; k < 8; ++k) {
                ag[0][k] += bf2fs(u0[k]);
                ag[1][k] += bf2fs(u1[k]);
                ag[2][k] += bf2fs(u2[k]);
                ag[3][k] += bf2fs(u3[k]);
            }
        }
    }
    short8 a1[4];
    {
        float sc = inv_deg[r];
#pragma unroll
        for (int s = 0; s < 4; ++s)
#pragma unroll
            for (int k = 0; k < 8; ++k)
                a1[s][k] = (short)f2bf(ag[s][k] * sc);
    }
    __syncthreads();

    f32x4 acc[3];
#pragma unroll
    for (int t = 0; t < 3; ++t) acc[t] = (f32x4){0.f, 0.f, 0.f, 0.f};

#pragma unroll
    for (int arr = 0; arr < 2; ++arr) {
        const uint16_t* WL = &ldsW[arr * 12288];
#pragma unroll
        for (int s = 0; s < 4; ++s) {
            short8 av;
            if (arr == 0) av = a1[s];
            else av = *(const short8*)&Ain[(size_t)r * 128 + s * 32 + g4 * 8];
#pragma unroll
            for (int t = 0; t < 3; ++t) {
                int off = (t * 16 + li) * 128 + (((s * 4 + g4) ^ li) << 3);
                short8 bh = *(const short8*)&WL[off];
                short8 bl = *(const short8*)&WL[off + 6144];
                acc[t] = __builtin_amdgcn_mfma_f32_16x16x32_bf16(av, bh, acc[t], 0, 0, 0);
                acc[t] = __builtin_amdgcn_mfma_f32_16x16x32_bf16(av, bl, acc[t], 0, 0, 0);
            }
        }
    }

    float b0 = bias[li];
    float b1 = bias[16 + li];
    bool v2ok = (li < 15);
    float b2 = v2ok ? bias[32 + li] : 0.f;

    int rowbase = blockIdx.x * 128 + wv * 16 + g4 * 4;
#pragma unroll
    for (int rr = 0; rr < 4; ++rr) {
        int row = rowbase + rr;
        float v0 = acc[0][rr] + b0;
        float v1 = acc[1][rr] + b1;
        float v2 = v2ok ? (acc[2][rr] + b2) : 0.f;
        float ss = v0 * v0 + v1 * v1 + v2 * v2;
        ss += __shfl_xor(ss, 1);
        ss += __shfl_xor(ss, 2);
        ss += __shfl_xor(ss, 4);
        ss += __shfl_xor(ss, 8);
        float inv = 1.f / fmaxf(sqrtf(ss), 1e-12f);
        v0 *= inv; v1 *= inv; v2 *= inv;
        float mx = fmaxf(v0, v1);
        if (v2ok) mx = fmaxf(mx, v2);
        mx = fmaxf(mx, __shfl_xor(mx, 1));
        mx = fmaxf(mx, __shfl_xor(mx, 2));
        mx = fmaxf(mx, __shfl_xor(mx, 4));
        mx = fmaxf(mx, __shfl_xor(mx, 8));
        float se = expf(v0 - mx) + expf(v1 - mx) + (v2ok ? expf(v2 - mx) : 0.f);
        se += __shfl_xor(se, 1);
        se += __shfl_xor(se, 2);
        se += __shfl_xor(se, 4);
        se += __shfl_xor(se, 8);
        float lse = logf(se);
        if (row < N_NODES) {
            size_t ob = (size_t)row * NCLS;
            out[ob + li]      = v0 - mx - lse;
            out[ob + 16 + li] = v1 - mx - lse;
            if (v2ok) out[ob + 32 + li] = v2 - mx - lse;
        }
    }
}

// ---------------------------------------------------------------------------
extern "C" void kernel_launch(void* const* d_in, const int* in_sizes, int n_in,
                              void* d_out, int out_size, void* d_ws, size_t ws_size,
                              hipStream_t stream) {
    const float* x   = (const float*)d_in[0];
    const int*   ei  = (const int*)d_in[1];
    const float* Wl0 = (const float*)d_in[2];
    const float* bl0 = (const float*)d_in[3];
    const float* Wr0 = (const float*)d_in[4];
    const float* Wl1 = (const float*)d_in[5];
    const float* bl1 = (const float*)d_in[6];
    const float* Wr1 = (const float*)d_in[7];
    const float* Wl2 = (const float*)d_in[8];
    const float* bl2 = (const float*)d_in[9];
    const float* Wr2 = (const float*)d_in[10];
    float* out = (float*)d_out;

    char* ws = (char*)d_ws;
    size_t cur = 0;
    auto alloc = [&](size_t bytes) {
        char* p = ws + cur;
        cur += (bytes + 255) & ~(size_t)255;
        return p;
    };
    const size_t MATB = (size_t)N_NODES * 128 * 2;   // bf16 matrix bytes
    int*      deg       = (int*)alloc(N_NODES * 4);
    int*      row_start = (int*)alloc(N_NODES * 4);
    int*      fill      = (int*)alloc(N_NODES * 4);
    float*    inv_deg   = (float*)alloc(N_NODES * 4);
    int*      partial   = (int*)alloc(SCAN_BLOCKS * 4);
    int*      elist     = (int*)alloc(N_EDGES * 4);
    uint16_t* wimg      = (uint16_t*)alloc(155648 * 2);
    uint16_t* xh        = (uint16_t*)alloc(MATB);
    uint16_t* Bh        = (uint16_t*)alloc(MATB);
    uint16_t* Ch        = (uint16_t*)alloc(MATB);

    hipMemsetAsync(deg, 0, N_NODES * 4, stream);
    k_prepw<<<384, 256, 0, stream>>>(Wl0, Wr0, Wl1, Wr1, Wl2, Wr2, wimg);
    k_split<<<(N_NODES * 128 / 4) / 256, 256, 0, stream>>>((const float4*)x, (ushort4*)xh);

    int egrid = (N_EDGES + 255) / 256;
    k_deg<<<egrid, 256, 0, stream>>>(ei, deg);
    k_scan1<<<SCAN_BLOCKS, SCAN_TPB, 0, stream>>>(deg, partial);
    k_scan2<<<1, 128, 0, stream>>>(partial);
    k_scan3<<<SCAN_BLOCKS, SCAN_TPB, 0, stream>>>(deg, partial, row_start, fill, inv_deg);
    k_fill<<<egrid, 256, 0, stream>>>(ei, fill, elist);

    int ggrid = (N_NODES + 127) / 128;       // 391

    // layer 0: Bh = relu(agg(xh)@Wl0 + xh@Wr0 + b)
    k_gemm<<<ggrid, 512, 0, stream>>>(xh, row_start, deg, inv_deg, elist,
                                      wimg, wimg + 32768, bl0, Bh);
    // layer 1: Ch = relu(agg(Bh)@Wl1 + Bh@Wr1 + b)
    k_gemm<<<ggrid, 512, 0, stream>>>(Bh, row_start, deg, inv_deg, elist,
                                      wimg + 65536, wimg + 98304, bl1, Ch);
    // layer 2: out = logsoftmax(normalize(agg(Ch)@Wl2 + Ch@Wr2 + b))
    k_gemm2<<<ggrid, 512, 0, stream>>>(Ch, row_start, deg, inv_deg, elist,
                                       wimg + 131072, bl2, out);
}

// Round 14
// 286.897 us; speedup vs baseline: 1.0165x; 1.0165x over previous
//
#include <hip/hip_runtime.h>
#include <stdint.h>

#define N_NODES 50000
#define N_EDGES 600000
#define NCLS    47
#define SCAN_TPB 512
#define SCAN_BLOCKS ((N_NODES + SCAN_TPB - 1) / SCAN_TPB)   // 98

typedef __attribute__((ext_vector_type(8))) short short8;
typedef __attribute__((ext_vector_type(4))) float f32x4;

static __device__ __forceinline__ float bf2f(uint16_t h) {
    union { uint32_t u; float f; } c; c.u = ((uint32_t)h) << 16; return c.f;
}
static __device__ __forceinline__ float bf2fs(short h) { return bf2f((uint16_t)h); }
static __device__ __forceinline__ uint16_t f2bf(float f) {
    union { float f; uint32_t u; } c; c.f = f;
    uint32_t u = c.u;
    return (uint16_t)((u + 0x7fffu + ((u >> 16) & 1u)) >> 16); // RNE
}

#define GLOAD_LDS16(gp, lp) \
    __builtin_amdgcn_global_load_lds( \
        (const __attribute__((address_space(1))) void*)(gp), \
        (__attribute__((address_space(3))) void*)(lp), 16, 0, 0)

// ---------------- f32 matrix -> bf16 (hi only)
__global__ __launch_bounds__(256) void k_split(const float4* __restrict__ x,
                                               ushort4* __restrict__ xh) {
    int i = blockIdx.x * 256 + threadIdx.x;   // 1.6M float4s
    float4 v = x[i];
    ushort4 h;
    h.x = f2bf(v.x);
    h.y = f2bf(v.y);
    h.z = f2bf(v.z);
    h.w = f2bf(v.w);
    xh[i] = h;
}

// ---------- degree count straight from edge_index (int64-or-int32)
__global__ __launch_bounds__(256) void k_deg(const int* __restrict__ ei,
                                             int* __restrict__ deg) {
    __shared__ int is64;
    {
        int lane = threadIdx.x;
        if (lane < 64) {
            int f = ei[2 * lane + 1] | ei[2 * lane + 129]; // 128 hi-words if int64
            unsigned long long m = __ballot(f != 0);
            if (lane == 0) is64 = (m == 0ULL) ? 1 : 0;
        }
        __syncthreads();
    }
    int e = blockIdx.x * 256 + threadIdx.x;
    if (e < N_EDGES) {
        int d = is64 ? ei[2 * (N_EDGES + e)] : ei[N_EDGES + e];
        d = min(max(d, 0), N_NODES - 1);
        atomicAdd(&deg[d], 1);
    }
}

// ------------------------------------------- scan stage 1: per-block partials
__global__ __launch_bounds__(SCAN_TPB) void k_scan1(const int* __restrict__ deg,
                                                    int* __restrict__ partial) {
    int t = blockIdx.x * SCAN_TPB + threadIdx.x;
    int v = (t < N_NODES) ? deg[t] : 0;
#pragma unroll
    for (int o = 1; o < 64; o <<= 1) v += __shfl_xor(v, o);
    __shared__ int ws[SCAN_TPB / 64];
    int lane = threadIdx.x & 63, w = threadIdx.x >> 6;
    if (lane == 0) ws[w] = v;
    __syncthreads();
    if (threadIdx.x == 0) {
        int s = 0;
#pragma unroll
        for (int i = 0; i < SCAN_TPB / 64; ++i) s += ws[i];
        partial[blockIdx.x] = s;
    }
}

// ---------------------------- scan stage 2: exclusive scan of 98 partials
__global__ __launch_bounds__(128) void k_scan2(int* __restrict__ partial) {
    __shared__ int sh[128];
    int t = threadIdx.x;
    int v = (t < SCAN_BLOCKS) ? partial[t] : 0;
    sh[t] = v;
    __syncthreads();
    for (int o = 1; o < 128; o <<= 1) {
        int u = (t >= o) ? sh[t - o] : 0;
        __syncthreads();
        sh[t] += u;
        __syncthreads();
    }
    if (t < SCAN_BLOCKS) partial[t] = sh[t] - v; // exclusive
}

// --------------- scan stage 3: block-local exclusive scan + offset, emit CSR
__global__ __launch_bounds__(SCAN_TPB) void k_scan3(const int* __restrict__ deg,
                                                    const int* __restrict__ partial,
                                                    int* __restrict__ row_start,
                                                    int* __restrict__ fill,
                                                    float* __restrict__ inv_deg) {
    int tb = threadIdx.x;
    int t = blockIdx.x * SCAN_TPB + tb;
    int v = (t < N_NODES) ? deg[t] : 0;
    int lane = tb & 63, w = tb >> 6;
    int inc = v;
#pragma unroll
    for (int o = 1; o < 64; o <<= 1) {
        int u = __shfl_up(inc, o);
        if (lane >= o) inc += u;
    }
    __shared__ int wsum[SCAN_TPB / 64];
    if (lane == 63) wsum[w] = inc;
    __syncthreads();
    int woff = 0;
    for (int i = 0; i < w; ++i) woff += wsum[i];
    int excl = partial[blockIdx.x] + woff + (inc - v);
    if (t < N_NODES) {
        row_start[t] = excl;
        fill[t] = excl;
        inv_deg[t] = 1.0f / (float)(v > 0 ? v : 1);
    }
}

// --------------------------- bucket fill (reads edge_index directly)
__global__ __launch_bounds__(256) void k_fill(const int* __restrict__ ei,
                                              int* __restrict__ fill,
                                              int* __restrict__ elist) {
    __shared__ int is64;
    {
        int lane = threadIdx.x;
        if (lane < 64) {
            int f = ei[2 * lane + 1] | ei[2 * lane + 129];
            unsigned long long m = __ballot(f != 0);
            if (lane == 0) is64 = (m == 0ULL) ? 1 : 0;
        }
        __syncthreads();
    }
    int e = blockIdx.x * 256 + threadIdx.x;
    if (e < N_EDGES) {
        int s, d;
        if (is64) { s = ei[2 * e]; d = ei[2 * (N_EDGES + e)]; }
        else      { s = ei[e];     d = ei[N_EDGES + e]; }
        s = min(max(s, 0), N_NODES - 1);
        d = min(max(d, 0), N_NODES - 1);
        int pos = atomicAdd(&fill[d], 1);
        elist[pos] = s;
    }
}

// -------------- weight prep: transpose W[k][col] -> img[col][k], bf16 hi + lo
// ALL matrices get the bank-conflict swizzle baked in: chunk (k>>3) ^ (col&15).
__global__ __launch_bounds__(256) void k_prepw(const float* Wl0, const float* Wr0,
                                               const float* Wl1, const float* Wr1,
                                               const float* Wl2, const float* Wr2,
                                               uint16_t* __restrict__ img) {
    int b = blockIdx.x >> 6;
    int sub = blockIdx.x & 63;
    const float* W; int ncol, npad; uint16_t* o;
    switch (b) {
        case 0: W = Wl0; ncol = 128; npad = 128; o = img;           break;
        case 1: W = Wr0; ncol = 128; npad = 128; o = img + 32768;   break;
        case 2: W = Wl1; ncol = 128; npad = 128; o = img + 65536;   break;
        case 3: W = Wr1; ncol = 128; npad = 128; o = img + 98304;   break;
        case 4: W = Wl2; ncol = 47;  npad = 48;  o = img + 131072;  break;
        default:W = Wr2; ncol = 47;  npad = 48;  o = img + 143360;  break;
    }
    int elems = npad * 128;
    int i = sub * 256 + threadIdx.x;
    if (i < elems) {
        int col = i % npad, k = i / npad;
        float v = (col < ncol) ? W[k * ncol + col] : 0.f;
        uint16_t h = f2bf(v);
        uint16_t l = f2bf(v - bf2f(h));
        int idx = col * 128 + (((k >> 3) ^ (col & 15)) << 3) + (k & 7);
        o[idx] = h;
        o[idx + elems] = l;
    }
}

// shared gather body: lane (li,g4) aggregates row r0's elems {s*32+g4*8+k}
// 4-edge unroll = 16 row-loads in flight per lane.
#define GATHER_BODY(Ain, r0, g4, ag)                                          \
    {                                                                         \
        int rs = row_start[r0];                                               \
        int d = degv[r0];                                                     \
        int i = 0;                                                            \
        for (; i + 3 < d; i += 4) {                                           \
            int n0 = elist[rs + i];                                           \
            int n1 = elist[rs + i + 1];                                       \
            int n2 = elist[rs + i + 2];                                       \
            int n3 = elist[rs + i + 3];                                       \
            const uint16_t* p0 = &Ain[(size_t)n0 * 128 + g4 * 8];             \
            const uint16_t* p1 = &Ain[(size_t)n1 * 128 + g4 * 8];             \
            const uint16_t* p2 = &Ain[(size_t)n2 * 128 + g4 * 8];             \
            const uint16_t* p3 = &Ain[(size_t)n3 * 128 + g4 * 8];             \
            short8 u0 = *(const short8*)&p0[0],  u1 = *(const short8*)&p0[32];\
            short8 u2 = *(const short8*)&p0[64], u3 = *(const short8*)&p0[96];\
            short8 v0 = *(const short8*)&p1[0],  v1 = *(const short8*)&p1[32];\
            short8 v2 = *(const short8*)&p1[64], v3 = *(const short8*)&p1[96];\
            short8 w0 = *(const short8*)&p2[0],  w1 = *(const short8*)&p2[32];\
            short8 w2 = *(const short8*)&p2[64], w3 = *(const short8*)&p2[96];\
            short8 x0 = *(const short8*)&p3[0],  x1 = *(const short8*)&p3[32];\
            short8 x2 = *(const short8*)&p3[64], x3 = *(const short8*)&p3[96];\
            _Pragma("unroll")                                                 \
            for (int k = 0; k < 8; ++k) {                                     \
                ag[0][k] += (bf2fs(u0[k]) + bf2fs(v0[k])) + (bf2fs(w0[k]) + bf2fs(x0[k])); \
                ag[1][k] += (bf2fs(u1[k]) + bf2fs(v1[k])) + (bf2fs(w1[k]) + bf2fs(x1[k])); \
                ag[2][k] += (bf2fs(u2[k]) + bf2fs(v2[k])) + (bf2fs(w2[k]) + bf2fs(x2[k])); \
                ag[3][k] += (bf2fs(u3[k]) + bf2fs(v3[k])) + (bf2fs(w3[k]) + bf2fs(x3[k])); \
            }                                                                 \
        }                                                                     \
        for (; i < d; ++i) {                                                  \
            int n0 = elist[rs + i];                                           \
            const uint16_t* p0 = &Ain[(size_t)n0 * 128 + g4 * 8];             \
            short8 u0 = *(const short8*)&p0[0],  u1 = *(const short8*)&p0[32];\
            short8 u2 = *(const short8*)&p0[64], u3 = *(const short8*)&p0[96];\
            _Pragma("unroll")                                                 \
            for (int k = 0; k < 8; ++k) {                                     \
                ag[0][k] += bf2fs(u0[k]);                                     \
                ag[1][k] += bf2fs(u1[k]);                                     \
                ag[2][k] += bf2fs(u2[k]);                                     \
                ag[3][k] += bf2fs(u3[k]);                                     \
            }                                                                 \
        }                                                                     \
    }

// ------- FUSED layers 0/1: out = relu(agg(Ain)@Wl + Ain@Wr + b)
// 512 thr / 8 waves / 16 rows/wave / 128 rows/block (grid 391), LDS-W.
// wl staged via async global_load_lds BEFORE the gather (overlaps it).
__global__ __launch_bounds__(512, 4) void k_gemm(const uint16_t* __restrict__ Ain,
                                                 const int* __restrict__ row_start,
                                                 const int* __restrict__ degv,
                                                 const float* __restrict__ inv_deg,
                                                 const int* __restrict__ elist,
                                                 const uint16_t* __restrict__ wl,
                                                 const uint16_t* __restrict__ wr,
                                                 const float* __restrict__ bias,
                                                 uint16_t* __restrict__ outh) {
    __shared__ __align__(16) uint16_t ldsW[32768];   // 64 KB: one matrix hi+lo
    int tid = threadIdx.x;
    int lane = tid & 63, wv = tid >> 6;              // 8 waves
    int li = lane & 15, g4 = lane >> 4;
    int mrow = blockIdx.x * 128 + wv * 16 + li;
    int r0 = min(mrow, N_NODES - 1);

    // issue async wl staging (DMA overlaps the gather below)
    {
        const char* g = (const char*)wl;
        char* l = (char*)ldsW;
        int off = tid * 16;
#pragma unroll
        for (int j2 = 0; j2 < 8; ++j2)
            GLOAD_LDS16(g + j2 * 8192 + off, l + j2 * 8192 + off);
    }

    // ---- phase 1: in-register mean aggregation of row r0's fragment elems
    float ag[4][8];
#pragma unroll
    for (int s = 0; s < 4; ++s)
#pragma unroll
        for (int k = 0; k < 8; ++k) ag[s][k] = 0.f;
    GATHER_BODY(Ain, r0, g4, ag)
    short8 a1[4];
    {
        float sc = inv_deg[r0];
#pragma unroll
        for (int s = 0; s < 4; ++s)
#pragma unroll
            for (int k = 0; k < 8; ++k)
                a1[s][k] = (short)f2bf(ag[s][k] * sc);
    }

    f32x4 acc[8];
#pragma unroll
    for (int t = 0; t < 8; ++t) acc[t] = (f32x4){0.f, 0.f, 0.f, 0.f};

    __syncthreads();   // wl DMA drained + all waves ready
#pragma unroll
    for (int s = 0; s < 4; ++s) {
#pragma unroll
        for (int t = 0; t < 8; ++t) {
            int off = (t * 16 + li) * 128 + (((s * 4 + g4) ^ li) << 3);
            short8 bh = *(const short8*)&ldsW[off];
            short8 bl = *(const short8*)&ldsW[off + 16384];
            acc[t] = __builtin_amdgcn_mfma_f32_16x16x32_bf16(a1[s], bh, acc[t], 0, 0, 0);
            acc[t] = __builtin_amdgcn_mfma_f32_16x16x32_bf16(a1[s], bl, acc[t], 0, 0, 0);
        }
    }
    __syncthreads();   // all waves done with wl
    {   // async wr staging
        const char* g = (const char*)wr;
        char* l = (char*)ldsW;
        int off = tid * 16;
#pragma unroll
        for (int j2 = 0; j2 < 8; ++j2)
            GLOAD_LDS16(g + j2 * 8192 + off, l + j2 * 8192 + off);
    }
    __syncthreads();   // wr DMA drained
#pragma unroll
    for (int s = 0; s < 4; ++s) {
        short8 av = *(const short8*)&Ain[(size_t)r0 * 128 + s * 32 + g4 * 8];
#pragma unroll
        for (int t = 0; t < 8; ++t) {
            int off = (t * 16 + li) * 128 + (((s * 4 + g4) ^ li) << 3);
            short8 bh = *(const short8*)&ldsW[off];
            short8 bl = *(const short8*)&ldsW[off + 16384];
            acc[t] = __builtin_amdgcn_mfma_f32_16x16x32_bf16(av, bh, acc[t], 0, 0, 0);
            acc[t] = __builtin_amdgcn_mfma_f32_16x16x32_bf16(av, bl, acc[t], 0, 0, 0);
        }
    }
    // epilogue: bias + relu, bf16 store.  D layout: col=lane&15, row=(lane>>4)*4+rr
    int rowbase = blockIdx.x * 128 + wv * 16 + g4 * 4;
#pragma unroll
    for (int t = 0; t < 8; ++t) {
        int col = t * 16 + li;
        float bv = bias[col];
#pragma unroll
        for (int rr = 0; rr < 4; ++rr) {
            int row = rowbase + rr;
            if (row < N_NODES)
                outh[(size_t)row * 128 + col] = f2bf(fmaxf(acc[t][rr] + bv, 0.f));
        }
    }
}

// -------- FUSED layer 2: logsoftmax(normalize(agg(Ain)@Wl2 + Ain@Wr2 + b))
__global__ __launch_bounds__(512, 4) void k_gemm2(const uint16_t* __restrict__ Ain,
                                                  const int* __restrict__ row_start,
                                                  const int* __restrict__ degv,
                                                  const float* __restrict__ inv_deg,
                                                  const int* __restrict__ elist,
                                                  const uint16_t* __restrict__ w2,
                                                  const float* __restrict__ bias,
                                                  float* __restrict__ out) {
    __shared__ __align__(16) uint16_t ldsW[24576];   // 48 KB: wl2+wr2, hi+lo
    int tid = threadIdx.x;
    int lane = tid & 63, wv = tid >> 6;
    int li = lane & 15, g4 = lane >> 4;
    int mrow = blockIdx.x * 128 + wv * 16 + li;
    int r = min(mrow, N_NODES - 1);

    {   // async-stage both layer-2 images (overlaps gather)
        const char* g = (const char*)w2;
        char* l = (char*)ldsW;
        int off = tid * 16;
#pragma unroll
        for (int j2 = 0; j2 < 6; ++j2)
            GLOAD_LDS16(g + j2 * 8192 + off, l + j2 * 8192 + off);
    }

    // ---- phase 1: in-register aggregation (overlaps with staging above)
    float ag[4][8];
#pragma unroll
    for (int s = 0; s < 4; ++s)
#pragma unroll
        for (int k = 0; k < 8; ++k) ag[s][k] = 0.f;
    GATHER_BODY(Ain, r, g4, ag)
    short8 a1[4];
    {
        float sc = inv_deg[r];
#pragma unroll
        for (int s = 0; s < 4; ++s)
#pragma unroll
            for (int k = 0; k < 8; ++k)
                a1[s][k] = (short)f2bf(ag[s][k] * sc);
    }
    __syncthreads();

    f32x4 acc[3];
#pragma unroll
    for (int t = 0; t < 3; ++t) acc[t] = (f32x4){0.f, 0.f, 0.f, 0.f};

#pragma unroll
    for (int arr = 0; arr < 2; ++arr) {
        const uint16_t* WL = &ldsW[arr * 12288];
#pragma unroll
        for (int s = 0; s < 4; ++s) {
            short8 av;
            if (arr == 0) av = a1[s];
            else av = *(const short8*)&Ain[(size_t)r * 128 + s * 32 + g4 * 8];
#pragma unroll
            for (int t = 0; t < 3; ++t) {
                int off = (t * 16 + li) * 128 + (((s * 4 + g4) ^ li) << 3);
                short8 bh = *(const short8*)&WL[off];
                short8 bl = *(const short8*)&WL[off + 6144];
                acc[t] = __builtin_amdgcn_mfma_f32_16x16x32_bf16(av, bh, acc[t], 0, 0, 0);
                acc[t] = __builtin_amdgcn_mfma_f32_16x16x32_bf16(av, bl, acc[t], 0, 0, 0);
            }
        }
    }

    float b0 = bias[li];
    float b1 = bias[16 + li];
    bool v2ok = (li < 15);
    float b2 = v2ok ? bias[32 + li] : 0.f;

    int rowbase = blockIdx.x * 128 + wv * 16 + g4 * 4;
#pragma unroll
    for (int rr = 0; rr < 4; ++rr) {
        int row = rowbase + rr;
        float v0 = acc[0][rr] + b0;
        float v1 = acc[1][rr] + b1;
        float v2 = v2ok ? (acc[2][rr] + b2) : 0.f;
        float ss = v0 * v0 + v1 * v1 + v2 * v2;
        ss += __shfl_xor(ss, 1);
        ss += __shfl_xor(ss, 2);
        ss += __shfl_xor(ss, 4);
        ss += __shfl_xor(ss, 8);
        float inv = 1.f / fmaxf(sqrtf(ss), 1e-12f);
        v0 *= inv; v1 *= inv; v2 *= inv;
        float mx = fmaxf(v0, v1);
        if (v2ok) mx = fmaxf(mx, v2);
        mx = fmaxf(mx, __shfl_xor(mx, 1));
        mx = fmaxf(mx, __shfl_xor(mx, 2));
        mx = fmaxf(mx, __shfl_xor(mx, 4));
        mx = fmaxf(mx, __shfl_xor(mx, 8));
        float se = expf(v0 - mx) + expf(v1 - mx) + (v2ok ? expf(v2 - mx) : 0.f);
        se += __shfl_xor(se, 1);
        se += __shfl_xor(se, 2);
        se += __shfl_xor(se, 4);
        se += __shfl_xor(se, 8);
        float lse = logf(se);
        if (row < N_NODES) {
            size_t ob = (size_t)row * NCLS;
            out[ob + li]      = v0 - mx - lse;
            out[ob + 16 + li] = v1 - mx - lse;
            if (v2ok) out[ob + 32 + li] = v2 - mx - lse;
        }
    }
}

// ---------------------------------------------------------------------------
extern "C" void kernel_launch(void* const* d_in, const int* in_sizes, int n_in,
                              void* d_out, int out_size, void* d_ws, size_t ws_size,
                              hipStream_t stream) {
    const float* x   = (const float*)d_in[0];
    const int*   ei  = (const int*)d_in[1];
    const float* Wl0 = (const float*)d_in[2];
    const float* bl0 = (const float*)d_in[3];
    const float* Wr0 = (const float*)d_in[4];
    const float* Wl1 = (const float*)d_in[5];
    const float* bl1 = (const float*)d_in[6];
    const float* Wr1 = (const float*)d_in[7];
    const float* Wl2 = (const float*)d_in[8];
    const float* bl2 = (const float*)d_in[9];
    const float* Wr2 = (const float*)d_in[10];
    float* out = (float*)d_out;

    char* ws = (char*)d_ws;
    size_t cur = 0;
    auto alloc = [&](size_t bytes) {
        char* p = ws + cur;
        cur += (bytes + 255) & ~(size_t)255;
        return p;
    };
    const size_t MATB = (size_t)N_NODES * 128 * 2;   // bf16 matrix bytes
    int*      deg       = (int*)alloc(N_NODES * 4);
    int*      row_start = (int*)alloc(N_NODES * 4);
    int*      fill      = (int*)alloc(N_NODES * 4);
    float*    inv_deg   = (float*)alloc(N_NODES * 4);
    int*      partial   = (int*)alloc(SCAN_BLOCKS * 4);
    int*      elist     = (int*)alloc(N_EDGES * 4);
    uint16_t* wimg      = (uint16_t*)alloc(155648 * 2);
    uint16_t* xh        = (uint16_t*)alloc(MATB);
    uint16_t* Bh        = (uint16_t*)alloc(MATB);
    uint16_t* Ch        = (uint16_t*)alloc(MATB);

    hipMemsetAsync(deg, 0, N_NODES * 4, stream);
    k_prepw<<<384, 256, 0, stream>>>(Wl0, Wr0, Wl1, Wr1, Wl2, Wr2, wimg);
    k_split<<<(N_NODES * 128 / 4) / 256, 256, 0, stream>>>((const float4*)x, (ushort4*)xh);

    int egrid = (N_EDGES + 255) / 256;
    k_deg<<<egrid, 256, 0, stream>>>(ei, deg);
    k_scan1<<<SCAN_BLOCKS, SCAN_TPB, 0, stream>>>(deg, partial);
    k_scan2<<<1, 128, 0, stream>>>(partial);
    k_scan3<<<SCAN_BLOCKS, SCAN_TPB, 0, stream>>>(deg, partial, row_start, fill, inv_deg);
    k_fill<<<egrid, 256, 0, stream>>>(ei, fill, elist);

    int ggrid = (N_NODES + 127) / 128;       // 391

    // layer 0: Bh = relu(agg(xh)@Wl0 + xh@Wr0 + b)
    k_gemm<<<ggrid, 512, 0, stream>>>(xh, row_start, deg, inv_deg, elist,
                                      wimg, wimg + 32768, bl0, Bh);
    // layer 1: Ch = relu(agg(Bh)@Wl1 + Bh@Wr1 + b)
    k_gemm<<<ggrid, 512, 0, stream>>>(Bh, row_start, deg, inv_deg, elist,
                                      wimg + 65536, wimg + 98304, bl1, Ch);
    // layer 2: out = logsoftmax(normalize(agg(Ch)@Wl2 + Ch@Wr2 + b))
    k_gemm2<<<ggrid, 512, 0, stream>>>(Ch, row_start, deg, inv_deg, elist,
                                       wimg + 131072, bl2, out);
}